// Round 15
// baseline (214.427 us; speedup 1.0000x reference)
//
#include <hip/hip_runtime.h>
#include <hip/hip_bf16.h>

// ---------- types / helpers ----------
typedef __attribute__((ext_vector_type(4))) float f32x4;   // MFMA C/D frag
typedef __attribute__((ext_vector_type(4))) int   int4v;   // one 16B load
typedef __attribute__((ext_vector_type(8))) int   int8v;   // K=128 fp8 A/B frag (32B)

// float -> OCP e4m3fn byte (cold path: weight prep only)
__device__ __forceinline__ unsigned char f2fp8(float f) {
    unsigned char s = (__float_as_uint(f) >> 24) & 0x80;
    float a = fabsf(f);
    if (a >= 448.f) return s | 0x7E;
    if (a < 0.015625f) {                       // subnormal: step 2^-9
        int q = (int)(a * 512.0f + 0.5f);
        return s | (unsigned char)q;
    }
    unsigned int u = __float_as_uint(a);
    u += 0x0007FFFF + ((u >> 20) & 1);         // RNE to 3 mantissa bits (carry-safe)
    int e8 = (int)((u >> 23) & 0xFF) - 120;    // -127+7
    if (e8 >= 16) return s | 0x7E;
    return s | (unsigned char)((e8 << 3) | ((u >> 20) & 7));
}
__device__ __forceinline__ void gload_lds16(const void* g, void* l) {
    // async global->LDS, 16B/lane; LDS dest = wave-uniform base + lane*16 (linear!)
    __builtin_amdgcn_global_load_lds((const __attribute__((address_space(1))) void*)g,
                                     (__attribute__((address_space(3))) void*)l, 16, 0, 0);
}
__device__ __forceinline__ int8v lds_frag32(const char* p) {   // 32B aligned LDS read
    union { int4v h[2]; int8v v; } u;
    u.h[0] = *(const int4v*)p;
    u.h[1] = *(const int4v*)(p + 16);
    return u.v;
}

// ---------- constants ----------
#define BATCH 256
#define CHAN  768
#define HW    196
#define SPS   196
#define HID   512
#define MROWS 50176   // BATCH*SPS
#define K1    1536    // 2*CHAN
#define WSCL  64.0f           // weights pre-scaled by 64 (e4m3 subnormal dodge)
#define WINV  0.015625f       // 1/64 applied after each GEMM
#define SC1   0x7F7F7F7F      // E8M0 scale 1.0 in every byte

// Fused MLP geometry: BM=64 rows/block, BN=512 (FULL width -> GEMM2 fusable),
// BK=128B; 256 threads = 4 waves, each owning 64x128 (acc[4][8]).
// LDS (72KB/block -> 2 blocks/CU): GEMM1 [A 8KB | B 64KB]; GEMM2 reuses as
// [h1 64x512 fp8 = 32KB | B2 panel 16KB].

// ---------- weight prep: in [K][N] fp32 -> out [N][K] fp8 of (w * 64) ----------
__global__ void transpose_cast_fp8(const float* __restrict__ in, unsigned char* __restrict__ out,
                                   int K, int N) {
    int idx = blockIdx.x * 256 + threadIdx.x;
    if (idx >= K * N) return;
    int n = idx / K, k = idx - n * K;
    out[idx] = f2fp8(in[(size_t)k * N + n] * WSCL);
}

// ---------- gather: feats fp8 via HW cvt_pk, 4B packed stores; deltaxy out ----------
__global__ __launch_bounds__(256) void gather_feats(const float* __restrict__ x,
                                                    const int* __restrict__ pxs,
                                                    const int* __restrict__ pys,
                                                    unsigned char* __restrict__ feats,
                                                    float* __restrict__ out) {
    __shared__ float lds[64 * 197];   // pitch 197: conflict-free
    int chunk = blockIdx.x;           // 0..11 (64-channel chunk)
    int b     = blockIdx.y;           // 0..255
    int c0 = chunk * 64;
    const float* xb = x + ((size_t)b * CHAN + c0) * HW;
    for (int t = threadIdx.x; t < 64 * HW; t += 256) {
        int j = t / HW, p = t - j * HW;
        lds[j * 197 + p] = xb[t];     // coalesced read of 64 full channels
    }
    if (chunk == 0) {                 // per-batch: deltaxy (pred written by fused kernel)
        for (int i = threadIdx.x; i < SPS * 2; i += 256) {
            int idx = b * SPS * 2 + i;
            out[MROWS * 2 + idx] = (float)(pxs[idx] - pys[idx]) + 13.0f;  // (H-1)=13
        }
    }
    __syncthreads();
    int wid = threadIdx.x >> 6, lane = threadIdx.x & 63;
    int g = lane >> 4;                // s-offset within the 4-s pack
    int cq = (lane & 15) * 4;         // channel quad
    for (int sb = wid * 4; sb < SPS; sb += 16) {
        int s = sb + g;
        int base = (b * SPS + s) * 2;
        int ix = pxs[base] * 14 + pxs[base + 1];
        int iy = pys[base] * 14 + pys[base + 1];
        const float* lx = lds + cq * 197;
        unsigned int ux = 0, uy = 0;
        ux = __builtin_amdgcn_cvt_pk_fp8_f32(lx[ix],       lx[197 + ix], ux, false);
        ux = __builtin_amdgcn_cvt_pk_fp8_f32(lx[394 + ix], lx[591 + ix], ux, true);
        uy = __builtin_amdgcn_cvt_pk_fp8_f32(lx[iy],       lx[197 + iy], uy, false);
        uy = __builtin_amdgcn_cvt_pk_fp8_f32(lx[394 + iy], lx[591 + iy], uy, true);
        size_t ro = (size_t)(b * SPS + s) * K1;
        *(unsigned int*)(feats + ro + c0 + cq)        = ux;
        *(unsigned int*)(feats + ro + CHAN + c0 + cq) = uy;
    }
}

// ---------- fused MLP: pred = relu(relu(feats@W1+b1)@W2+b2)@W3 + b3 ----------
// Block owns rows [bid*64, +64).  Phase 1: h1-block (64x512) over K1=1536 (12 tiles,
// serial-staged A+B; 2 blocks/CU overlap each other's drains).  Phase 2: h1 -> LDS fp8,
// then 16 panels of 32 W2-cols: h2 = relu(h1@W2p+b2); pred += h2@W3p.  Rows are
// block-exclusive -> direct store with b3 (no atomics).
__global__ __launch_bounds__(256, 2) void mlp_fused(const unsigned char* __restrict__ feats,
                                                    const unsigned char* __restrict__ W1t,
                                                    const float* __restrict__ b1,
                                                    const unsigned char* __restrict__ W2t,
                                                    const float* __restrict__ b2,
                                                    const float* __restrict__ W3,
                                                    const float* __restrict__ b3,
                                                    float* __restrict__ out) {
    extern __shared__ char smem[];    // 73728 B
    const int t = threadIdx.x;
    const int wid = t >> 6, lane = t & 63;
    const int lr = lane & 15, lk = lane >> 4;
    const int mBase = blockIdx.x * 64;
    f32x4 acc[4][8] = {};

    char* Ab = smem;                  // 8KB: A tile 64 x 128B
    char* Bb = smem + 8192;           // 64KB: B tile 512 x 128B

    // ---- Phase 1: GEMM1, 12 K-tiles, serial stage ----
    for (int kt = 0; kt < 12; ++kt) {
        #pragma unroll
        for (int i = 0; i < 2; ++i) {             // A: 512 units x 16B = 8KB
            int lin = i * 256 + t, row = lin >> 3, cs = lin & 7;
            gload_lds16(feats + (size_t)(mBase + row) * K1 + kt * 128 + cs * 16,
                        Ab + lin * 16);
        }
        #pragma unroll
        for (int i = 0; i < 16; ++i) {            // B: 4096 units x 16B = 64KB
            int lin = i * 256 + t, row = lin >> 3, cs = lin & 7;
            gload_lds16(W1t + (size_t)row * K1 + kt * 128 + cs * 16,
                        Bb + lin * 16);
        }
        __syncthreads();                          // drain: tile resident
        int8v af[4];
        #pragma unroll
        for (int m = 0; m < 4; ++m)
            af[m] = lds_frag32(Ab + (m * 16 + lr) * 128 + lk * 32);
        #pragma unroll
        for (int half = 0; half < 2; ++half) {
            int8v bf4[4];
            #pragma unroll
            for (int n = 0; n < 4; ++n)
                bf4[n] = lds_frag32(Bb + (wid * 128 + (half * 4 + n) * 16 + lr) * 128 + lk * 32);
            #pragma unroll
            for (int m = 0; m < 4; ++m)
                #pragma unroll
                for (int n = 0; n < 4; ++n)
                    acc[m][half * 4 + n] = __builtin_amdgcn_mfma_scale_f32_16x16x128_f8f6f4(
                        af[m], bf4[n], acc[m][half * 4 + n], 0, 0, 0, SC1, 0, SC1);
        }
        __syncthreads();                          // all reads done before next stage
    }

    // ---- handoff: h1 = relu(acc/64 + b1) -> LDS fp8 [64 rows][512B] ----
    char* h1l = smem;                 // 32KB (overwrites dead A/B-front)
    char* B2b = smem + 32768;         // 16KB panel (within dead B region)
    #pragma unroll
    for (int n = 0; n < 8; ++n) {
        int c = wid * 128 + n * 16 + lr;
        float bv = b1[c];
        #pragma unroll
        for (int m = 0; m < 4; ++m) {
            int r0 = m * 16 + lk * 4;
            float v0 = fmaxf(acc[m][n][0] * WINV + bv, 0.f);
            float v1 = fmaxf(acc[m][n][1] * WINV + bv, 0.f);
            float v2 = fmaxf(acc[m][n][2] * WINV + bv, 0.f);
            float v3 = fmaxf(acc[m][n][3] * WINV + bv, 0.f);
            unsigned int u = __builtin_amdgcn_cvt_pk_fp8_f32(v0, v1, 0u, false);
            u = __builtin_amdgcn_cvt_pk_fp8_f32(v2, v3, u, true);
            h1l[(r0 + 0) * 512 + c] = (unsigned char)(u & 0xff);
            h1l[(r0 + 1) * 512 + c] = (unsigned char)((u >> 8) & 0xff);
            h1l[(r0 + 2) * 512 + c] = (unsigned char)((u >> 16) & 0xff);
            h1l[(r0 + 3) * 512 + c] = (unsigned char)((u >> 24) & 0xff);
        }
    }

    // ---- Phase 2: GEMM2 (+GEMM3 fold), 16 panels x 32 cols ----
    float pp0[4] = {0.f, 0.f, 0.f, 0.f}, pp1[4] = {0.f, 0.f, 0.f, 0.f};
    for (int p = 0; p < 16; ++p) {
        #pragma unroll
        for (int i = 0; i < 4; ++i) {             // B2: 1024 units x 16B = 16KB
            int lin = i * 256 + t, row2 = lin >> 5, cs2 = lin & 31;
            gload_lds16(W2t + (size_t)(p * 32 + row2) * 512 + cs2 * 16,
                        B2b + lin * 16);
        }
        __syncthreads();              // drains B2 gloads (+ h1 ds_writes on p=0)
        f32x4 acc2[2] = {};
        #pragma unroll
        for (int kt2 = 0; kt2 < 4; ++kt2) {
            int8v a2 = lds_frag32(h1l + (wid * 16 + lr) * 512 + kt2 * 128 + lk * 32);
            #pragma unroll
            for (int n2 = 0; n2 < 2; ++n2) {
                int8v b2f = lds_frag32(B2b + (n2 * 16 + lr) * 512 + kt2 * 128 + lk * 32);
                acc2[n2] = __builtin_amdgcn_mfma_scale_f32_16x16x128_f8f6f4(
                    a2, b2f, acc2[n2], 0, 0, 0, SC1, 0, SC1);
            }
        }
        #pragma unroll
        for (int n2 = 0; n2 < 2; ++n2) {
            int c2 = p * 32 + n2 * 16 + lr;
            float bv = b2[c2], w30 = W3[c2 * 2], w31 = W3[c2 * 2 + 1];
            #pragma unroll
            for (int j = 0; j < 4; ++j) {
                float v = fmaxf(acc2[n2][j] * WINV + bv, 0.f);
                pp0[j] += v * w30;
                pp1[j] += v * w31;
            }
        }
        __syncthreads();              // reads of B2b done before next stage
    }

    // ---- reduce over the 16 lr-lanes; direct store (rows block-exclusive) ----
    float bb0 = b3[0], bb1 = b3[1];
    #pragma unroll
    for (int j = 0; j < 4; ++j) {
        float p0 = pp0[j], p1 = pp1[j];
        #pragma unroll
        for (int msk = 1; msk < 16; msk <<= 1) {
            p0 += __shfl_xor(p0, msk);
            p1 += __shfl_xor(p1, msk);
        }
        if (lr == 0) {
            int r = mBase + wid * 16 + lk * 4 + j;
            out[(size_t)r * 2 + 0] = p0 + bb0;
            out[(size_t)r * 2 + 1] = p1 + bb1;
        }
    }
}

// ---------- launch ----------
extern "C" void kernel_launch(void* const* d_in, const int* in_sizes, int n_in,
                              void* d_out, int out_size, void* d_ws, size_t ws_size,
                              hipStream_t stream) {
    const float* x  = (const float*)d_in[0];
    const float* W1 = (const float*)d_in[1];
    const float* b1 = (const float*)d_in[2];
    const float* W2 = (const float*)d_in[3];
    const float* b2 = (const float*)d_in[4];
    const float* W3 = (const float*)d_in[5];
    const float* b3 = (const float*)d_in[6];
    const int*  pxs = (const int*)d_in[7];
    const int*  pys = (const int*)d_in[8];
    float* out = (float*)d_out;
    char* ws = (char*)d_ws;

    // ws layout (bytes): W1t 786,432 | W2t 262,144 | feats 77,070,336
    unsigned char* W1t   = (unsigned char*)(ws + 0);
    unsigned char* W2t   = (unsigned char*)(ws + 786432);
    unsigned char* feats = (unsigned char*)(ws + 1048576);   // end 78,118,912

    hipFuncSetAttribute((const void*)mlp_fused,
                        hipFuncAttributeMaxDynamicSharedMemorySize, 73728);

    transpose_cast_fp8<<<(K1 * HID + 255) / 256, 256, 0, stream>>>(W1, W1t, K1, HID);
    transpose_cast_fp8<<<(HID * HID + 255) / 256, 256, 0, stream>>>(W2, W2t, HID, HID);
    gather_feats<<<dim3(12, BATCH), 256, 0, stream>>>(x, pxs, pys, feats, out);
    // fused MLP: grid = 784 blocks x 64 rows
    mlp_fused<<<MROWS / 64, 256, 73728, stream>>>(feats, W1t, b1, W2t, b2, W3, b3, out);
}

// Round 16
// 166.349 us; speedup vs baseline: 1.2890x; 1.2890x over previous
//
#include <hip/hip_runtime.h>
#include <hip/hip_bf16.h>

// ---------- types / helpers ----------
typedef __attribute__((ext_vector_type(4))) float f32x4;   // MFMA C/D frag
typedef __attribute__((ext_vector_type(4))) int   int4v;   // one 16B load
typedef __attribute__((ext_vector_type(8))) int   int8v;   // K=128 fp8 A/B frag (32B)

// float -> OCP e4m3fn byte (cold path: weight prep only)
__device__ __forceinline__ unsigned char f2fp8(float f) {
    unsigned char s = (__float_as_uint(f) >> 24) & 0x80;
    float a = fabsf(f);
    if (a >= 448.f) return s | 0x7E;
    if (a < 0.015625f) {                       // subnormal: step 2^-9
        int q = (int)(a * 512.0f + 0.5f);
        return s | (unsigned char)q;
    }
    unsigned int u = __float_as_uint(a);
    u += 0x0007FFFF + ((u >> 20) & 1);         // RNE to 3 mantissa bits (carry-safe)
    int e8 = (int)((u >> 23) & 0xFF) - 120;    // -127+7
    if (e8 >= 16) return s | 0x7E;
    return s | (unsigned char)((e8 << 3) | ((u >> 20) & 7));
}
__device__ __forceinline__ void gload_lds16(const void* g, void* l) {
    // async global->LDS, 16B/lane; LDS dest = wave-uniform base + lane*16 (linear!)
    __builtin_amdgcn_global_load_lds((const __attribute__((address_space(1))) void*)g,
                                     (__attribute__((address_space(3))) void*)l, 16, 0, 0);
}

// ---------- constants ----------
#define BATCH 256
#define CHAN  768
#define HW    196
#define SPS   196
#define HID   512
#define MROWS 50176   // BATCH*SPS
#define K1    1536    // 2*CHAN
#define WSCL  64.0f           // weights pre-scaled by 64 (e4m3 subnormal dodge)
#define WINV  0.015625f       // 1/64 applied after each GEMM
#define SC1   0x7F7F7F7F      // E8M0 scale 1.0 in every byte

// Fused MLP: BM=128 rows/block, BN=512 (full width), BK=128B; 512 threads = 8 waves
// (2M x 4N), per-wave 64x128 (acc[4][8]).  LDS 160KB exact, 1 block/CU:
//   Phase 1: [A0 16K | A1 16K | B0 64K | B1 64K]  (full double-buffer, issue-early)
//   Phase 2: [B2p0 16K | B2p1 16K | h1 64K @32768 | (B1 dead)]
// Phase-2 rows are 512B (bank-aligned stride) -> 16B XOR swizzle slot = chunk^(row&31)
// (inverse on gload source / on h1-write; forward on frag reads) -> conflict-free.

// ---------- weight prep: in [K][N] fp32 -> out [N][K] fp8 of (w * 64) ----------
__global__ void transpose_cast_fp8(const float* __restrict__ in, unsigned char* __restrict__ out,
                                   int K, int N) {
    int idx = blockIdx.x * 256 + threadIdx.x;
    if (idx >= K * N) return;
    int n = idx / K, k = idx - n * K;
    out[idx] = f2fp8(in[(size_t)k * N + n] * WSCL);
}

// ---------- gather: feats fp8 via HW cvt_pk, 4B packed stores; deltaxy out ----------
__global__ __launch_bounds__(256) void gather_feats(const float* __restrict__ x,
                                                    const int* __restrict__ pxs,
                                                    const int* __restrict__ pys,
                                                    unsigned char* __restrict__ feats,
                                                    float* __restrict__ out) {
    __shared__ float lds[64 * 197];   // pitch 197: conflict-free
    int chunk = blockIdx.x;           // 0..11 (64-channel chunk)
    int b     = blockIdx.y;           // 0..255
    int c0 = chunk * 64;
    const float* xb = x + ((size_t)b * CHAN + c0) * HW;
    for (int t = threadIdx.x; t < 64 * HW; t += 256) {
        int j = t / HW, p = t - j * HW;
        lds[j * 197 + p] = xb[t];     // coalesced read of 64 full channels
    }
    if (chunk == 0) {                 // per-batch: deltaxy (pred written by fused kernel)
        for (int i = threadIdx.x; i < SPS * 2; i += 256) {
            int idx = b * SPS * 2 + i;
            out[MROWS * 2 + idx] = (float)(pxs[idx] - pys[idx]) + 13.0f;  // (H-1)=13
        }
    }
    __syncthreads();
    int wid = threadIdx.x >> 6, lane = threadIdx.x & 63;
    int g = lane >> 4;                // s-offset within the 4-s pack
    int cq = (lane & 15) * 4;         // channel quad
    for (int sb = wid * 4; sb < SPS; sb += 16) {
        int s = sb + g;
        int base = (b * SPS + s) * 2;
        int ix = pxs[base] * 14 + pxs[base + 1];
        int iy = pys[base] * 14 + pys[base + 1];
        const float* lx = lds + cq * 197;
        unsigned int ux = 0, uy = 0;
        ux = __builtin_amdgcn_cvt_pk_fp8_f32(lx[ix],       lx[197 + ix], ux, false);
        ux = __builtin_amdgcn_cvt_pk_fp8_f32(lx[394 + ix], lx[591 + ix], ux, true);
        uy = __builtin_amdgcn_cvt_pk_fp8_f32(lx[iy],       lx[197 + iy], uy, false);
        uy = __builtin_amdgcn_cvt_pk_fp8_f32(lx[394 + iy], lx[591 + iy], uy, true);
        size_t ro = (size_t)(b * SPS + s) * K1;
        *(unsigned int*)(feats + ro + c0 + cq)        = ux;
        *(unsigned int*)(feats + ro + CHAN + c0 + cq) = uy;
    }
}

// ---------- fused MLP: pred = relu(relu(feats@W1+b1)@W2+b2)@W3 + b3 ----------
__global__ __launch_bounds__(512, 1) void mlp_fused(const unsigned char* __restrict__ feats,
                                                    const unsigned char* __restrict__ W1t,
                                                    const float* __restrict__ b1,
                                                    const unsigned char* __restrict__ W2t,
                                                    const float* __restrict__ b2,
                                                    const float* __restrict__ W3,
                                                    const float* __restrict__ b3,
                                                    float* __restrict__ out) {
    extern __shared__ char smem[];    // 163840 B
    const int t = threadIdx.x;
    const int wid = t >> 6, lane = t & 63;
    const int wr = wid >> 2, wcn = wid & 3;   // 2M x 4N waves; wave owns 64 rows x 128 cols
    const int lr = lane & 15, lk = lane >> 4;
    const int mBase = blockIdx.x * 128;
    f32x4 acc[4][8] = {};

    // ---- Phase 1: GEMM1, 12 K-tiles, full dbuf, issue-early (R14-proven loop) ----
    // A tiles at 0/16384 (16KB each), B tiles at 32768/98304 (64KB each).
    auto stage1 = [&](int buf, int kt) {
        char* Ab = smem + buf * 16384;
        char* Bb = smem + 32768 + buf * 65536;
        #pragma unroll
        for (int i = 0; i < 2; ++i) {             // A: 1024 units = 128 rows x 128B
            int lin = i * 512 + t, row = lin >> 3, cs = (lin & 7) ^ (row & 7);
            gload_lds16(feats + (size_t)(mBase + row) * K1 + kt * 128 + cs * 16,
                        Ab + lin * 16);
        }
        #pragma unroll
        for (int i = 0; i < 8; ++i) {             // B: 4096 units = 512 rows x 128B
            int lin = i * 512 + t, row = lin >> 3, cs = (lin & 7) ^ (row & 7);
            gload_lds16(W1t + (size_t)row * K1 + kt * 128 + cs * 16,
                        Bb + lin * 16);
        }
    };
    auto frag128 = [&](const char* rowp, int r) -> int8v {   // swizzled 32B frag, 128B row
        union { int4v h[2]; int8v v; } u;
        u.h[0] = *(const int4v*)(rowp + (((2 * lk + 0) ^ (r & 7)) * 16));
        u.h[1] = *(const int4v*)(rowp + (((2 * lk + 1) ^ (r & 7)) * 16));
        return u.v;
    };
    auto compute1 = [&](int buf) {
        const char* Ab = smem + buf * 16384;
        const char* Bb = smem + 32768 + buf * 65536;
        int8v af[4];
        #pragma unroll
        for (int m = 0; m < 4; ++m) {
            int r = wr * 64 + m * 16 + lr;
            af[m] = frag128(Ab + r * 128, r);
        }
        #pragma unroll
        for (int half = 0; half < 2; ++half) {
            int8v bf4[4];
            #pragma unroll
            for (int n = 0; n < 4; ++n) {
                int r = wcn * 128 + (half * 4 + n) * 16 + lr;
                bf4[n] = frag128(Bb + r * 128, r);
            }
            #pragma unroll
            for (int m = 0; m < 4; ++m)
                #pragma unroll
                for (int n = 0; n < 4; ++n)
                    acc[m][half * 4 + n] = __builtin_amdgcn_mfma_scale_f32_16x16x128_f8f6f4(
                        af[m], bf4[n], acc[m][half * 4 + n], 0, 0, 0, SC1, 0, SC1);
        }
    };

    stage1(0, 0);
    __syncthreads();
    int cur = 0;
    for (int kt = 0; kt < 12; ++kt) {
        if (kt + 1 < 12) stage1(cur ^ 1, kt + 1);   // flies under compute(kt)
        compute1(cur);
        __syncthreads();
        cur ^= 1;
    }
    // ledger: last tile (kt=11) read from buf1 (A1/B1); B0 (32768..98304) and A0/A1
    // are dead -> h1 over B0, B2 panels over A0/A1.

    // ---- handoff: h1 = relu(acc/64 + b1) -> LDS fp8, rows 512B, swizzled ----
    char* h1l = smem + 32768;         // 64KB: [128 rows][512B], slot = chunk^(r&31)
    char* B2b0 = smem;                // 16KB panel buffers over dead A0/A1
    char* B2b1 = smem + 16384;
    #pragma unroll
    for (int n = 0; n < 8; ++n) {
        int c = wcn * 128 + n * 16 + lr;
        int c16 = wcn * 8 + n;        // c>>4 (lr<16)
        float bv = b1[c];
        #pragma unroll
        for (int m = 0; m < 4; ++m) {
            int r0 = wr * 64 + m * 16 + lk * 4;
            float v0 = fmaxf(acc[m][n][0] * WINV + bv, 0.f);
            float v1 = fmaxf(acc[m][n][1] * WINV + bv, 0.f);
            float v2 = fmaxf(acc[m][n][2] * WINV + bv, 0.f);
            float v3 = fmaxf(acc[m][n][3] * WINV + bv, 0.f);
            unsigned int u = __builtin_amdgcn_cvt_pk_fp8_f32(v0, v1, 0u, false);
            u = __builtin_amdgcn_cvt_pk_fp8_f32(v2, v3, u, true);
            #pragma unroll
            for (int j = 0; j < 4; ++j) {
                int r = r0 + j;
                h1l[r * 512 + ((c16 ^ (r & 31)) * 16) + lr] =
                    (unsigned char)((u >> (8 * j)) & 0xff);
            }
        }
    }

    // ---- Phase 2: GEMM2 (+GEMM3 fold), 16 panels x 32 cols, dbuf'd panels ----
    auto stageB2 = [&](char* dst, int p) {
        #pragma unroll
        for (int i = 0; i < 2; ++i) {             // 1024 units = 32 rows x 512B
            int lin = i * 512 + t, row2 = lin >> 5, c = lin & 31;
            gload_lds16(W2t + (size_t)(p * 32 + row2) * 512 + ((c ^ row2) * 16),
                        dst + lin * 16);
        }
    };
    auto frag512 = [&](const char* base, int r, int kt2) -> int8v {  // swizzled, 512B row
        int g = kt2 * 8 + lk * 2;
        union { int4v h[2]; int8v v; } u;
        u.h[0] = *(const int4v*)(base + r * 512 + (((g + 0) ^ (r & 31)) * 16));
        u.h[1] = *(const int4v*)(base + r * 512 + (((g + 1) ^ (r & 31)) * 16));
        return u.v;
    };

    float pp0[4] = {0.f, 0.f, 0.f, 0.f}, pp1[4] = {0.f, 0.f, 0.f, 0.f};
    stageB2(B2b0, 0);
    __syncthreads();                  // h1 ds_writes + B2(0) resident
    for (int p = 0; p < 16; ++p) {
        char* curB = (p & 1) ? B2b1 : B2b0;
        char* nxtB = (p & 1) ? B2b0 : B2b1;
        if (p + 1 < 16) stageB2(nxtB, p + 1);      // flies under compute(p)
        f32x4 acc2[2] = {};
        #pragma unroll
        for (int kt2 = 0; kt2 < 4; ++kt2) {
            int8v a2 = frag512(h1l, wid * 16 + lr, kt2);
            #pragma unroll
            for (int n2 = 0; n2 < 2; ++n2) {
                int8v b2f = frag512(curB, n2 * 16 + lr, kt2);
                acc2[n2] = __builtin_amdgcn_mfma_scale_f32_16x16x128_f8f6f4(
                    a2, b2f, acc2[n2], 0, 0, 0, SC1, 0, SC1);
            }
        }
        #pragma unroll
        for (int n2 = 0; n2 < 2; ++n2) {
            int c2 = p * 32 + n2 * 16 + lr;
            float bv = b2[c2], w30 = W3[c2 * 2], w31 = W3[c2 * 2 + 1];
            #pragma unroll
            for (int j = 0; j < 4; ++j) {
                float v = fmaxf(acc2[n2][j] * WINV + bv, 0.f);
                pp0[j] += v * w30;
                pp1[j] += v * w31;
            }
        }
        __syncthreads();              // curB reads done before it is restaged
    }

    // ---- reduce over the 16 lr-lanes; direct store (rows block-exclusive) ----
    float bb0 = b3[0], bb1 = b3[1];
    #pragma unroll
    for (int j = 0; j < 4; ++j) {
        float p0 = pp0[j], p1 = pp1[j];
        #pragma unroll
        for (int msk = 1; msk < 16; msk <<= 1) {
            p0 += __shfl_xor(p0, msk);
            p1 += __shfl_xor(p1, msk);
        }
        if (lr == 0) {
            int r = mBase + wid * 16 + lk * 4 + j;
            out[(size_t)r * 2 + 0] = p0 + bb0;
            out[(size_t)r * 2 + 1] = p1 + bb1;
        }
    }
}

// ---------- launch ----------
extern "C" void kernel_launch(void* const* d_in, const int* in_sizes, int n_in,
                              void* d_out, int out_size, void* d_ws, size_t ws_size,
                              hipStream_t stream) {
    const float* x  = (const float*)d_in[0];
    const float* W1 = (const float*)d_in[1];
    const float* b1 = (const float*)d_in[2];
    const float* W2 = (const float*)d_in[3];
    const float* b2 = (const float*)d_in[4];
    const float* W3 = (const float*)d_in[5];
    const float* b3 = (const float*)d_in[6];
    const int*  pxs = (const int*)d_in[7];
    const int*  pys = (const int*)d_in[8];
    float* out = (float*)d_out;
    char* ws = (char*)d_ws;

    // ws layout (bytes): W1t 786,432 | W2t 262,144 | feats 77,070,336
    unsigned char* W1t   = (unsigned char*)(ws + 0);
    unsigned char* W2t   = (unsigned char*)(ws + 786432);
    unsigned char* feats = (unsigned char*)(ws + 1048576);   // end 78,118,912

    hipFuncSetAttribute((const void*)mlp_fused,
                        hipFuncAttributeMaxDynamicSharedMemorySize, 163840);

    transpose_cast_fp8<<<(K1 * HID + 255) / 256, 256, 0, stream>>>(W1, W1t, K1, HID);
    transpose_cast_fp8<<<(HID * HID + 255) / 256, 256, 0, stream>>>(W2, W2t, HID, HID);
    gather_feats<<<dim3(12, BATCH), 256, 0, stream>>>(x, pxs, pys, feats, out);
    // fused MLP: grid = 392 blocks x 128 rows, 512 threads, 160KB LDS
    mlp_fused<<<MROWS / 128, 512, 163840, stream>>>(feats, W1t, b1, W2t, b2, W3, b3, out);
}